// Round 3
// 546.296 us; speedup vs baseline: 1.0430x; 1.0430x over previous
//
#include <hip/hip_runtime.h>

// Problem constants
#define SE_B   64
#define SE_C   384
#define SE_CH  96
#define SE_HW  3136   // 56*56
#define SE_HW4 784    // HW / 4 (float4 count per row); 784 = 12*64 + 16
#define SE_ROWS (SE_B * SE_C)   // 24576
#define SE_BLOCKS (SE_ROWS / 4) // 6144: one wave per row, 4 waves/block

typedef float floatx4 __attribute__((ext_vector_type(4)));

// Kernel 1: global average pool. One wave per (b,c) row.
// Explicit 12-deep load batch + predicated tail => 12-13 independent loads
// in flight per wave (a lane-dependent-trip-count loop keeps ~1-2).
// Regular (caching) loads on purpose: leaves x resident in L3 for kernel 3.
__global__ __launch_bounds__(256) void se_pool_kernel(const float* __restrict__ x,
                                                      float* __restrict__ se) {
    const int wave = threadIdx.x >> 6;
    const int lane = threadIdx.x & 63;
    const int row  = blockIdx.x * 4 + wave;   // b*C + c
    const floatx4* __restrict__ xr = (const floatx4*)(x + (size_t)row * SE_HW);

    floatx4 v[12];
    #pragma unroll
    for (int j = 0; j < 12; ++j) v[j] = xr[lane + j * 64];
    floatx4 t = {0.f, 0.f, 0.f, 0.f};
    if (lane < 16) t = xr[768 + lane];

    float sum = (t.x + t.y) + (t.z + t.w);
    #pragma unroll
    for (int j = 0; j < 12; ++j) sum += (v[j].x + v[j].y) + (v[j].z + v[j].w);

    #pragma unroll
    for (int off = 32; off > 0; off >>= 1) sum += __shfl_xor(sum, off, 64);
    if (lane == 0) se[row] = sum * (1.0f / SE_HW);
}

// Kernel 2: MLP layer 1 (reduce + ReLU). One wave per (b,k) output:
// 6144 waves / 1536 blocks vs a 64-block kernel that leaves 192 CUs idle.
// Lane l reads float2 columns {l, l+64, l+128} (of 192) of both the se-row
// and the w_reduce-row (fully coalesced), then a 6-step shuffle reduce.
__global__ __launch_bounds__(256) void se_mlp1_kernel(const float* __restrict__ se,
                                                      const float* __restrict__ w_reduce,
                                                      const float* __restrict__ b_reduce,
                                                      float* __restrict__ h) {
    const int wave = threadIdx.x >> 6;
    const int lane = threadIdx.x & 63;
    const int o = blockIdx.x * 4 + wave;      // o = b*CH + k, 0..6143
    const int b = o / SE_CH;
    const int k = o - b * SE_CH;
    const float2* __restrict__ sr = (const float2*)(se + b * SE_C);
    const float2* __restrict__ wr = (const float2*)(w_reduce + (size_t)k * SE_C);

    float sum = 0.f;
    #pragma unroll
    for (int j = 0; j < 3; ++j) {
        float2 s = sr[lane + j * 64];
        float2 w = wr[lane + j * 64];
        sum = fmaf(s.x, w.x, sum);
        sum = fmaf(s.y, w.y, sum);
    }
    #pragma unroll
    for (int off = 32; off > 0; off >>= 1) sum += __shfl_xor(sum, off, 64);
    if (lane == 0) h[o] = fmaxf(sum + b_reduce[k], 0.f);
}

// Kernel 3: fused {MLP layer 2 + sigmoid} prologue + gated scale.
// Layer 2 per wave is a 96-dot over L2-hot h[b,:] and one w_expand row
// (~20 instructions), deleting the standalone layer-2 kernel and its
// launch/drain bubble. REVERSE block order so the first rows scaled are
// the rows pool touched last (still L3-resident). NT loads (x not reused
// after this) and NT stores (no RFO, don't evict x).
__global__ __launch_bounds__(256) void se_scale_kernel(const float* __restrict__ x,
                                                       const float* __restrict__ h,
                                                       const float* __restrict__ w_expand,
                                                       const float* __restrict__ b_expand,
                                                       float* __restrict__ out) {
    const int wave = threadIdx.x >> 6;
    const int lane = threadIdx.x & 63;
    const int row  = (SE_BLOCKS - 1 - blockIdx.x) * 4 + wave;  // b*C + c
    const int b = row / SE_C;
    const int c = row - b * SE_C;

    // gate = sigmoid(w_expand[c,:] . h[b,:] + b_expand[c])
    // Both 32-lane halves compute identical partials (l = lane&31, 3 elems
    // each); xor-reduce offsets 16..1 stay inside each half, so every lane
    // converges to the full 96-element dot without a broadcast.
    const float* __restrict__ hb = h + b * SE_CH;
    const float* __restrict__ we = w_expand + (size_t)c * SE_CH;
    const int l = lane & 31;
    float p = hb[l] * we[l];
    p = fmaf(hb[l + 32], we[l + 32], p);
    p = fmaf(hb[l + 64], we[l + 64], p);
    #pragma unroll
    for (int off = 16; off > 0; off >>= 1) p += __shfl_xor(p, off, 64);
    const float g = 1.0f / (1.0f + __expf(-(p + b_expand[c])));

    const floatx4* __restrict__ xr   = (const floatx4*)(x + (size_t)row * SE_HW);
    floatx4* __restrict__       orow = (floatx4*)(out + (size_t)row * SE_HW);

    // Batch all 12+tail loads before any store: the read burst runs ahead,
    // 12-13 loads in flight per wave instead of load->mul->store lockstep.
    floatx4 v[12];
    #pragma unroll
    for (int j = 0; j < 12; ++j) v[j] = __builtin_nontemporal_load(&xr[lane + j * 64]);
    floatx4 t = {0.f, 0.f, 0.f, 0.f};
    if (lane < 16) t = __builtin_nontemporal_load(&xr[768 + lane]);

    #pragma unroll
    for (int j = 0; j < 12; ++j) {
        floatx4 w = v[j] * g;
        __builtin_nontemporal_store(w, &orow[lane + j * 64]);
    }
    if (lane < 16) {
        floatx4 w = t * g;
        __builtin_nontemporal_store(w, &orow[768 + lane]);
    }
}

extern "C" void kernel_launch(void* const* d_in, const int* in_sizes, int n_in,
                              void* d_out, int out_size, void* d_ws, size_t ws_size,
                              hipStream_t stream) {
    const float* x        = (const float*)d_in[0];
    const float* w_reduce = (const float*)d_in[1];
    const float* b_reduce = (const float*)d_in[2];
    const float* w_expand = (const float*)d_in[3];
    const float* b_expand = (const float*)d_in[4];
    float* out = (float*)d_out;

    float* se = (float*)d_ws;          // B*C floats
    float* h  = se + SE_ROWS;          // B*CH floats

    se_pool_kernel<<<SE_BLOCKS, 256, 0, stream>>>(x, se);
    se_mlp1_kernel<<<(SE_B * SE_CH) / 4, 256, 0, stream>>>(se, w_reduce, b_reduce, h);
    se_scale_kernel<<<SE_BLOCKS, 256, 0, stream>>>(x, h, w_expand, b_expand, out);
}